// Round 2
// baseline (67.293 us; speedup 1.0000x reference)
//
#include <hip/hip_runtime.h>
#include <hip/hip_cooperative_groups.h>

namespace cg = cooperative_groups;

// Conv2d 3x3 pad1: x(2,64,112,112) f32, w(64,64,3,3) f32, bias(64) f32 -> out(2,64,112,112) f32
// Single cooperative kernel: phase1 = NCHW->padded-NHWC bf16 x-transform + [tap][oc][ic] bf16
// weights; grid.sync(); phase2 = implicit GEMM on mfma_f32_16x16x32_bf16 with the weight
// table staged in XOR-swizzled LDS. Fallback to 2 plain kernels if cooperative launch fails.

#define IN_C  64
#define OUT_C 64
#define BN    2
#define HH    112
#define WW    112
#define HP    114
#define WP    114
#define HW    (HH * WW)
#define NXROW (BN * HP)          // 228 x-prep jobs
#define NWBLK 36                 // 36 blocks * 256 thr * 1 float4 = 9216 float4 = all of w
#define NCONV 392                // 2 * 28 * 7 output tiles (4 rows x 16 cols, 4 waves)

typedef __attribute__((ext_vector_type(8))) short          bf16x8;
typedef __attribute__((ext_vector_type(8))) unsigned short u16x8;
typedef __attribute__((ext_vector_type(4))) float          f32x4;

static __device__ __forceinline__ unsigned short f2bf(float f) {
    unsigned int u = __builtin_bit_cast(unsigned int, f);
    u += 0x7FFFu + ((u >> 16) & 1u);   // round-nearest-even
    return (unsigned short)(u >> 16);
}

// ---- phase 1: x (B,64,112,112) f32 -> xt (B,114,114,64) bf16 (zero halo);
//               w (64,64,3,3) f32 -> wt[tap][oc][ic] bf16
static __device__ __forceinline__ void phase_prep(int blk, int tid,
                                                  const float* __restrict__ x,
                                                  const float* __restrict__ w,
                                                  unsigned short* __restrict__ xt,
                                                  unsigned short* __restrict__ wt) {
    if (blk < NXROW) {
        int b  = blk / HP;
        int yp = blk % HP;
        int xp = tid & 127;          // 0..127, valid < 114
        int cgp = tid >> 7;          // 0..1, 32 channels each
        if (xp < WP) {
            unsigned short* dst = xt + (((size_t)b * HP + yp) * WP + xp) * IN_C + cgp * 32;
            bool border = (yp == 0) | (yp == HP - 1) | (xp == 0) | (xp == WP - 1);
            if (border) {
                u16x8 z = {0, 0, 0, 0, 0, 0, 0, 0};
#pragma unroll
                for (int g = 0; g < 4; ++g)
                    *reinterpret_cast<u16x8*>(dst + g * 8) = z;
            } else {
                const float* src = x + ((size_t)b * IN_C + cgp * 32) * HW + (yp - 1) * WW + (xp - 1);
#pragma unroll
                for (int g = 0; g < 4; ++g) {
                    u16x8 v;
#pragma unroll
                    for (int j = 0; j < 8; ++j)
                        v[j] = f2bf(src[(size_t)(g * 8 + j) * HW]);
                    *reinterpret_cast<u16x8*>(dst + g * 8) = v;
                }
            }
        }
    } else if (blk < NXROW + NWBLK) {
        int t = (blk - NXROW) * 256 + tid;                 // 0..9215
        f32x4 v = reinterpret_cast<const f32x4*>(w)[t];
#pragma unroll
        for (int j = 0; j < 4; ++j) {
            int e   = 4 * t + j;                           // (oc*64+ic)*9 + tap
            int tap = e % 9;
            int p   = e / 9;                               // oc*64+ic
            wt[(size_t)tap * (OUT_C * IN_C) + p] = f2bf(v[j]);
        }
    }
}

// ---- phase 2: implicit GEMM. Wave = 16 px (one row segment) x 64 oc.
// B staged in LDS with XOR swizzle: short-col ^ ((row&7)<<3) keeps 16B align,
// spreads the 128B-stride rows across all eight 16B bank slots.
static __device__ __forceinline__ void phase_conv(int blk, int tid,
                                                  const unsigned short* __restrict__ xt,
                                                  const unsigned short* __restrict__ wt,
                                                  const float* __restrict__ bias,
                                                  float* __restrict__ out,
                                                  unsigned short* __restrict__ lw) {
    // stage wt (36864 shorts) -> swizzled LDS: 18 u16x8 per thread
#pragma unroll
    for (int i = 0; i < 18; ++i) {
        int V   = tid + i * 256;               // vec8 index, < 4608
        int row = V >> 3;                      // tap*64 + oc
        int c   = (V & 7) << 3;                // short col within row
        u16x8 v = *reinterpret_cast<const u16x8*>(wt + (size_t)V * 8);
        int cs  = c ^ ((row & 7) << 3);
        *reinterpret_cast<u16x8*>(&lw[row * 64 + cs]) = v;
    }
    __syncthreads();

    int l  = tid & 63;
    int wv = tid >> 6;                  // wave 0..3 -> row within ytile
    int b  = blk / 196;
    int rm = blk % 196;
    int ytile = rm / 7, xtile = rm % 7;
    int y  = ytile * 4 + wv;
    int x0 = xtile * 16;
    int lm = l & 15;
    int lk = l >> 4;
    int swz = (lm & 7) << 3;

    f32x4 acc0 = {0.f, 0.f, 0.f, 0.f};
    f32x4 acc1 = {0.f, 0.f, 0.f, 0.f};
    f32x4 acc2 = {0.f, 0.f, 0.f, 0.f};
    f32x4 acc3 = {0.f, 0.f, 0.f, 0.f};

    const unsigned short* xb = xt + (((size_t)b * HP + y) * WP + x0 + lm) * IN_C + lk * 8;

#pragma unroll
    for (int r = 0; r < 3; ++r) {
#pragma unroll
        for (int s = 0; s < 3; ++s) {
            const unsigned short* xp  = xb + (r * WP + s) * IN_C;
            int tapbase = ((r * 3 + s) * OUT_C + lm) * 64;   // row*64 for f=0
#pragma unroll
            for (int icc = 0; icc < 2; ++icc) {
                int cs = (icc * 32 + lk * 8) ^ swz;
                bf16x8 a  = *reinterpret_cast<const bf16x8*>(xp + icc * 32);
                bf16x8 b0 = *reinterpret_cast<const bf16x8*>(&lw[tapbase + cs]);
                bf16x8 b1 = *reinterpret_cast<const bf16x8*>(&lw[tapbase + 16 * 64 + cs]);
                bf16x8 b2 = *reinterpret_cast<const bf16x8*>(&lw[tapbase + 32 * 64 + cs]);
                bf16x8 b3 = *reinterpret_cast<const bf16x8*>(&lw[tapbase + 48 * 64 + cs]);
                acc0 = __builtin_amdgcn_mfma_f32_16x16x32_bf16(a, b0, acc0, 0, 0, 0);
                acc1 = __builtin_amdgcn_mfma_f32_16x16x32_bf16(a, b1, acc1, 0, 0, 0);
                acc2 = __builtin_amdgcn_mfma_f32_16x16x32_bf16(a, b2, acc2, 0, 0, 0);
                acc3 = __builtin_amdgcn_mfma_f32_16x16x32_bf16(a, b3, acc3, 0, 0, 0);
            }
        }
    }

    f32x4 accs[4] = {acc0, acc1, acc2, acc3};
    int px = x0 + lk * 4;
#pragma unroll
    for (int f = 0; f < 4; ++f) {
        int oc   = f * 16 + lm;
        float bv = bias[oc];
        f32x4 v  = accs[f];
        v.x += bv; v.y += bv; v.z += bv; v.w += bv;
        *reinterpret_cast<f32x4*>(out + (((size_t)b * OUT_C + oc) * HH + y) * WW + px) = v;
    }
}

// ---- single cooperative kernel ----
__global__ __launch_bounds__(256, 2) void fused_conv(const float* __restrict__ x,
                                                     const float* __restrict__ w,
                                                     const float* __restrict__ bias,
                                                     float* __restrict__ out,
                                                     unsigned short* __restrict__ xt,
                                                     unsigned short* __restrict__ wt) {
    __shared__ unsigned short lw[9 * OUT_C * IN_C];    // 73728 B
    int tid = threadIdx.x;
    int blk = blockIdx.x;
    phase_prep(blk, tid, x, w, xt, wt);
    cg::this_grid().sync();
    phase_conv(blk, tid, xt, wt, bias, out, lw);
}

// ---- fallback: two plain kernels ----
__global__ __launch_bounds__(256) void prep_all(const float* __restrict__ x,
                                                const float* __restrict__ w,
                                                unsigned short* __restrict__ xt,
                                                unsigned short* __restrict__ wt) {
    phase_prep(blockIdx.x, threadIdx.x, x, w, xt, wt);
}

__global__ __launch_bounds__(256) void conv_lds(const unsigned short* __restrict__ xt,
                                                const unsigned short* __restrict__ wt,
                                                const float* __restrict__ bias,
                                                float* __restrict__ out) {
    __shared__ unsigned short lw[9 * OUT_C * IN_C];
    phase_conv(blockIdx.x, threadIdx.x, xt, wt, bias, out, lw);
}

extern "C" void kernel_launch(void* const* d_in, const int* in_sizes, int n_in,
                              void* d_out, int out_size, void* d_ws, size_t ws_size,
                              hipStream_t stream) {
    const float* x    = (const float*)d_in[0];
    const float* w    = (const float*)d_in[1];
    const float* bias = (const float*)d_in[2];
    float* out        = (float*)d_out;

    unsigned short* xt = (unsigned short*)d_ws;                  // 2*114*114*64 bf16
    unsigned short* wt = xt + (size_t)BN * HP * WP * IN_C;       // 9*64*64 bf16

    void* args[] = {(void*)&x, (void*)&w, (void*)&bias, (void*)&out, (void*)&xt, (void*)&wt};
    hipError_t e = hipLaunchCooperativeKernel((const void*)fused_conv, dim3(NCONV), dim3(256),
                                              args, 0, stream);
    if (e != hipSuccess) {
        prep_all<<<dim3(NXROW + NWBLK), dim3(256), 0, stream>>>(x, w, xt, wt);
        conv_lds<<<dim3(NCONV), dim3(256), 0, stream>>>(xt, wt, bias, out);
    }
}

// Round 3
// 18.648 us; speedup vs baseline: 3.6086x; 3.6086x over previous
//
#include <hip/hip_runtime.h>

// Conv2d 3x3 pad1: x(2,64,112,112) f32, w(64,64,3,3) f32, bias(64) f32 -> out(2,64,112,112) f32
// Two kernels (no cooperative grid.sync — measured 53.6us with it, all pipes idle):
//   1) prep_all: NCHW->padded-NHWC bf16 x-transform (912 blocks, 8 loads/thread)
//                + [tap][oc][ic] bf16 weight transform (36 blocks)
//   2) conv_lds: implicit GEMM, mfma_f32_16x16x32_bf16, weights in XOR-swizzled LDS,
//                A-fragments direct 16B global loads from NHWC bf16.

#define IN_C  64
#define OUT_C 64
#define BN    2
#define HH    112
#define WW    112
#define HP    114
#define WP    114
#define HW    (HH * WW)
#define NXBLK (BN * HP * 4)      // 912: (b, yp, channel-quad)
#define NWBLK 36                 // 36 * 256 * f32x4 = all 36864 floats of w
#define NCONV 392                // 2 * 28 * 7 tiles (4 rows x 16 cols, 4 waves)

typedef __attribute__((ext_vector_type(8))) short          bf16x8;
typedef __attribute__((ext_vector_type(8))) unsigned short u16x8;
typedef __attribute__((ext_vector_type(4))) float          f32x4;

static __device__ __forceinline__ unsigned short f2bf(float f) {
    unsigned int u = __builtin_bit_cast(unsigned int, f);
    u += 0x7FFFu + ((u >> 16) & 1u);   // round-nearest-even
    return (unsigned short)(u >> 16);
}

// blocks [0, NXBLK): x-transform. block = (b, yp, cq); thread = (xp, 8-channel group).
// blocks [NXBLK, NXBLK+NWBLK): w-transform.
__global__ __launch_bounds__(256) void prep_all(const float* __restrict__ x,
                                                const float* __restrict__ w,
                                                unsigned short* __restrict__ xt,
                                                unsigned short* __restrict__ wt) {
    int blk = blockIdx.x;
    int tid = threadIdx.x;
    if (blk < NXBLK) {
        int cq = blk & 3;
        int r  = blk >> 2;
        int b  = r / HP;
        int yp = r % HP;
        int xp = tid & 127;                    // 0..127, valid < 114
        int ch = cq * 16 + (tid >> 7) * 8;     // 8 channels per thread
        if (xp >= WP) return;
        unsigned short* dst = xt + (((size_t)b * HP + yp) * WP + xp) * IN_C + ch;
        bool border = (yp == 0) | (yp == HP - 1) | (xp == 0) | (xp == WP - 1);
        if (border) {
            u16x8 z = {0, 0, 0, 0, 0, 0, 0, 0};
            *reinterpret_cast<u16x8*>(dst) = z;
        } else {
            const float* src = x + ((size_t)b * IN_C + ch) * HW + (yp - 1) * WW + (xp - 1);
            u16x8 v;
#pragma unroll
            for (int j = 0; j < 8; ++j)
                v[j] = f2bf(src[(size_t)j * HW]);
            *reinterpret_cast<u16x8*>(dst) = v;
        }
    } else {
        int t = (blk - NXBLK) * 256 + tid;     // 0..9215
        f32x4 v = reinterpret_cast<const f32x4*>(w)[t];
#pragma unroll
        for (int j = 0; j < 4; ++j) {
            int e   = 4 * t + j;               // (oc*64+ic)*9 + tap
            int tap = e % 9;
            int p   = e / 9;                   // oc*64+ic
            wt[(size_t)tap * (OUT_C * IN_C) + p] = f2bf(v[j]);
        }
    }
}

// Implicit GEMM: wave = 16 px (one row segment) x 64 oc, K=576.
// B staged in LDS, XOR-swizzled (short-col ^ ((row&7)<<3)) -> conflict-free ds_read_b128.
// A: 16B global loads from xt (NHWC, contiguous in ic).
// D layout (m89-verified): col(oc)=l&15, row(pixel)=4*(l>>4)+reg.
__global__ __launch_bounds__(256, 2) void conv_lds(const unsigned short* __restrict__ xt,
                                                   const unsigned short* __restrict__ wt,
                                                   const float* __restrict__ bias,
                                                   float* __restrict__ out) {
    __shared__ unsigned short lw[9 * OUT_C * IN_C];    // 73728 B
    int tid = threadIdx.x;
    int blk = blockIdx.x;

    // stage wt (36864 shorts): 18 u16x8 per thread, swizzled
#pragma unroll
    for (int i = 0; i < 18; ++i) {
        int V   = tid + i * 256;               // vec8 index, < 4608
        int row = V >> 3;                      // tap*64 + oc
        int c   = (V & 7) << 3;                // short col within row
        u16x8 v = *reinterpret_cast<const u16x8*>(wt + (size_t)V * 8);
        int cs  = c ^ ((row & 7) << 3);
        *reinterpret_cast<u16x8*>(&lw[row * 64 + cs]) = v;
    }
    __syncthreads();

    int l  = tid & 63;
    int wv = tid >> 6;                  // wave 0..3 -> row within ytile
    int b  = blk / 196;
    int rm = blk % 196;
    int ytile = rm / 7, xtile = rm % 7;
    int y  = ytile * 4 + wv;
    int x0 = xtile * 16;
    int lm = l & 15;
    int lk = l >> 4;
    int swz = (lm & 7) << 3;

    f32x4 acc0 = {0.f, 0.f, 0.f, 0.f};
    f32x4 acc1 = {0.f, 0.f, 0.f, 0.f};
    f32x4 acc2 = {0.f, 0.f, 0.f, 0.f};
    f32x4 acc3 = {0.f, 0.f, 0.f, 0.f};

    const unsigned short* xb = xt + (((size_t)b * HP + y) * WP + x0 + lm) * IN_C + lk * 8;

#pragma unroll
    for (int r = 0; r < 3; ++r) {
#pragma unroll
        for (int s = 0; s < 3; ++s) {
            const unsigned short* xp  = xb + (r * WP + s) * IN_C;
            int tapbase = ((r * 3 + s) * OUT_C + lm) * 64;   // row*64 for f=0
#pragma unroll
            for (int icc = 0; icc < 2; ++icc) {
                int cs = (icc * 32 + lk * 8) ^ swz;
                bf16x8 a  = *reinterpret_cast<const bf16x8*>(xp + icc * 32);
                bf16x8 b0 = *reinterpret_cast<const bf16x8*>(&lw[tapbase + cs]);
                bf16x8 b1 = *reinterpret_cast<const bf16x8*>(&lw[tapbase + 16 * 64 + cs]);
                bf16x8 b2 = *reinterpret_cast<const bf16x8*>(&lw[tapbase + 32 * 64 + cs]);
                bf16x8 b3 = *reinterpret_cast<const bf16x8*>(&lw[tapbase + 48 * 64 + cs]);
                acc0 = __builtin_amdgcn_mfma_f32_16x16x32_bf16(a, b0, acc0, 0, 0, 0);
                acc1 = __builtin_amdgcn_mfma_f32_16x16x32_bf16(a, b1, acc1, 0, 0, 0);
                acc2 = __builtin_amdgcn_mfma_f32_16x16x32_bf16(a, b2, acc2, 0, 0, 0);
                acc3 = __builtin_amdgcn_mfma_f32_16x16x32_bf16(a, b3, acc3, 0, 0, 0);
            }
        }
    }

    f32x4 accs[4] = {acc0, acc1, acc2, acc3};
    int px = x0 + lk * 4;
#pragma unroll
    for (int f = 0; f < 4; ++f) {
        int oc   = f * 16 + lm;
        float bv = bias[oc];
        f32x4 v  = accs[f];
        v.x += bv; v.y += bv; v.z += bv; v.w += bv;
        *reinterpret_cast<f32x4*>(out + (((size_t)b * OUT_C + oc) * HH + y) * WW + px) = v;
    }
}

extern "C" void kernel_launch(void* const* d_in, const int* in_sizes, int n_in,
                              void* d_out, int out_size, void* d_ws, size_t ws_size,
                              hipStream_t stream) {
    const float* x    = (const float*)d_in[0];
    const float* w    = (const float*)d_in[1];
    const float* bias = (const float*)d_in[2];
    float* out        = (float*)d_out;

    unsigned short* xt = (unsigned short*)d_ws;                  // 2*114*114*64 bf16 = 3,326,976 B
    unsigned short* wt = xt + (size_t)BN * HP * WP * IN_C;       // 9*64*64 bf16 = 73,728 B

    prep_all<<<dim3(NXBLK + NWBLK), dim3(256), 0, stream>>>(x, w, xt, wt);
    conv_lds<<<dim3(NCONV), dim3(256), 0, stream>>>(xt, wt, bias, out);
}